// Round 1
// 769.684 us; speedup vs baseline: 1.0746x; 1.0746x over previous
//
#include <hip/hip_runtime.h>
#include <stdint.h>

typedef unsigned short u16;
typedef __bf16 bf16x8 __attribute__((ext_vector_type(8)));
typedef float f32x4 __attribute__((ext_vector_type(4)));
typedef uint32_t u32x4 __attribute__((ext_vector_type(4)));

// ---- problem constants (fixed by the reference) ----
constexpr int P_  = 4, B_ = 2, S_ = 2048, D_ = 2048;
constexpr int H_  = 16, HK_ = 4, DH_ = 128;
constexpr int M_  = P_ * B_ * S_;            // 16384 rows of hidden_states
constexpr int NQKV = (H_ + 2 * HK_) * DH_;   // 3072 fused QKV columns
constexpr int K_  = D_;                      // 2048

__device__ __forceinline__ float bf2f(u16 u) {
  union { unsigned int i; float f; } v; v.i = ((unsigned int)u) << 16; return v.f;
}
__device__ __forceinline__ u16 f2bf(float f) {
  union { float f; unsigned int i; } v; v.f = f;
  unsigned int r = v.i + 0x7fffu + ((v.i >> 16) & 1u);  // RNE
  return (u16)(r >> 16);
}
__device__ __forceinline__ uint32_t pkbf(float lo, float hi) {
  return (uint32_t)f2bf(lo) | ((uint32_t)f2bf(hi) << 16);
}

// async global->LDS, 16B per lane; LDS dest is wave-uniform base + lane*16
__device__ __forceinline__ void gll16(const u16* g, u16* l) {
  __builtin_amdgcn_global_load_lds(
      (const __attribute__((address_space(1))) uint32_t*)g,
      (__attribute__((address_space(3))) uint32_t*)l, 16, 0, 0);
}

// ---------------------------------------------------------------------------
// Tiled transpose + fp32->bf16 convert: src fp32 (rows x cols) ->
// dst bf16 [dstOff + c*ld + r]
// ---------------------------------------------------------------------------
__global__ __launch_bounds__(256) void transpose_f32_bf16(
    const float* __restrict__ src, u16* __restrict__ dst,
    int rows, int cols, size_t dstOff, int ld) {
  __shared__ float tile[32][33];
  int c0 = blockIdx.x * 32, r0 = blockIdx.y * 32;
  int tx = threadIdx.x, ty = threadIdx.y;  // 32 x 8
#pragma unroll
  for (int i = 0; i < 32; i += 8)
    tile[ty + i][tx] = src[(size_t)(r0 + ty + i) * cols + (c0 + tx)];
  __syncthreads();
#pragma unroll
  for (int i = 0; i < 32; i += 8)
    dst[dstOff + (size_t)(c0 + ty + i) * ld + (r0 + tx)] = f2bf(tile[tx][ty + i]);
}

// fp32 -> bf16 bulk convert (vectorized, grid-stride): enables global_load_lds
// staging of A in the QKV GEMM.
__global__ __launch_bounds__(256) void f32_to_bf16(
    const float* __restrict__ src, u16* __restrict__ dst, size_t n8) {
  size_t i = (size_t)blockIdx.x * 256 + threadIdx.x;
  size_t stride = (size_t)gridDim.x * 256;
  for (; i < n8; i += stride) {
    f32x4 a = ((const f32x4*)src)[2 * i];
    f32x4 b = ((const f32x4*)src)[2 * i + 1];
    u32x4 o = (u32x4){pkbf(a[0], a[1]), pkbf(a[2], a[3]),
                      pkbf(b[0], b[1]), pkbf(b[2], b[3])};
    ((u32x4*)dst)[i] = o;
  }
}

// concat bq|bk|bv (fp32) -> bias[3072] fp32
__global__ void build_bias(const float* __restrict__ bq, const float* __restrict__ bk,
                           const float* __restrict__ bv, float* __restrict__ bias) {
  int n = blockIdx.x * 256 + threadIdx.x;
  if (n < NQKV)
    bias[n] = (n < H_ * DH_) ? bq[n]
            : (n < H_ * DH_ + HK_ * DH_) ? bk[n - H_ * DH_]
            : bv[n - H_ * DH_ - HK_ * DH_];
}

// ---------------------------------------------------------------------------
// FALLBACK ONLY (ws too small): old reg-staging GEMM with fp32 A.
// ---------------------------------------------------------------------------
template <bool AF32, bool OUTF32>
__global__ __launch_bounds__(256) void gemm_bt(
    const void* __restrict__ Av, int lda, const u16* __restrict__ BT,
    void* __restrict__ Cv, int N, int K, const float* __restrict__ bias) {
  __shared__ __align__(16) u16 As[128 * 32];
  __shared__ __align__(16) u16 Bs[128 * 32];

  const int tid  = threadIdx.x;
  const int wave = tid >> 6;
  const int lane = tid & 63;
  const int waveM = wave & 1, waveN = wave >> 1;

  const int mBase = blockIdx.y * 128;
  const int nBase = blockIdx.x * 128;

  const int l4 = lane >> 2;
  const int cg = (lane & 3) ^ ((lane >> 3) & 3);

  const float* agf0 = nullptr; const float* agf1 = nullptr;
  const u16*   agh0 = nullptr; const u16*   agh1 = nullptr;
  if (AF32) {
    agf0 = (const float*)Av + (size_t)(mBase + wave * 16 + l4) * lda + cg * 8;
    agf1 = agf0 + (size_t)64 * lda;
  } else {
    agh0 = (const u16*)Av + (size_t)(mBase + wave * 16 + l4) * lda + cg * 8;
    agh1 = agh0 + (size_t)64 * lda;
  }
  const u16* bg0 = BT + (size_t)(nBase + wave * 16 + l4) * K + cg * 8;
  const u16* bg1 = bg0 + (size_t)64 * K;
  u16* al0 = As + wave * 512 + lane * 8;
  u16* al1 = As + 2048 + wave * 512 + lane * 8;
  u16* bl0 = Bs + wave * 512 + lane * 8;
  u16* bl1 = Bs + 2048 + wave * 512 + lane * 8;

  const int tm = lane & 15;
  const int quad = lane >> 4;
  const int rslot = quad ^ ((tm >> 1) & 3);
  const u16* aRead = As + (waveM * 64 + tm) * 32 + rslot * 8;
  const u16* bRead = Bs + (waveN * 64 + tm) * 32 + rslot * 8;

  f32x4 acc[4][4];
#pragma unroll
  for (int i = 0; i < 4; i++)
#pragma unroll
    for (int j = 0; j < 4; j++) acc[i][j] = (f32x4){0.f, 0.f, 0.f, 0.f};

  for (int k0 = 0; k0 < K; k0 += 32) {
    u32x4 ra0, ra1;
    if (AF32) {
      f32x4 lo0 = *(const f32x4*)(agf0 + k0);
      f32x4 hi0 = *(const f32x4*)(agf0 + k0 + 4);
      f32x4 lo1 = *(const f32x4*)(agf1 + k0);
      f32x4 hi1 = *(const f32x4*)(agf1 + k0 + 4);
      ra0 = (u32x4){pkbf(lo0[0], lo0[1]), pkbf(lo0[2], lo0[3]),
                    pkbf(hi0[0], hi0[1]), pkbf(hi0[2], hi0[3])};
      ra1 = (u32x4){pkbf(lo1[0], lo1[1]), pkbf(lo1[2], lo1[3]),
                    pkbf(hi1[0], hi1[1]), pkbf(hi1[2], hi1[3])};
    } else {
      ra0 = *(const u32x4*)(agh0 + k0);
      ra1 = *(const u32x4*)(agh1 + k0);
    }
    u32x4 rb0 = *(const u32x4*)(bg0 + k0);
    u32x4 rb1 = *(const u32x4*)(bg1 + k0);
    __syncthreads();
    *(u32x4*)al0 = ra0;
    *(u32x4*)al1 = ra1;
    *(u32x4*)bl0 = rb0;
    *(u32x4*)bl1 = rb1;
    __syncthreads();

    bf16x8 af[4], bf[4];
#pragma unroll
    for (int i = 0; i < 4; i++) {
      af[i] = *(const bf16x8*)(aRead + i * 512);
      bf[i] = *(const bf16x8*)(bRead + i * 512);
    }
#pragma unroll
    for (int i = 0; i < 4; i++)
#pragma unroll
      for (int j = 0; j < 4; j++)
        acc[i][j] = __builtin_amdgcn_mfma_f32_16x16x32_bf16(af[i], bf[j], acc[i][j], 0, 0, 0);
  }

  float bi[4] = {0.f, 0.f, 0.f, 0.f};
  if (bias != nullptr) {
#pragma unroll
    for (int j = 0; j < 4; j++) bi[j] = bias[nBase + waveN * 64 + j * 16 + tm];
  }
#pragma unroll
  for (int i = 0; i < 4; i++) {
    int row0 = mBase + waveM * 64 + i * 16 + quad * 4;
#pragma unroll
    for (int j = 0; j < 4; j++) {
      int col = nBase + waveN * 64 + j * 16 + tm;
#pragma unroll
      for (int r = 0; r < 4; r++) {
        float v = acc[i][j][r] + bi[j];
        if (OUTF32)
          ((float*)Cv)[(size_t)(row0 + r) * N + col] = v;
        else
          ((u16*)Cv)[(size_t)(row0 + r) * N + col] = f2bf(v);
      }
    }
  }
}

// ---------------------------------------------------------------------------
// Main GEMM: C(M x N) = A(bf16, M x K [lda]) * BT(bf16, N x K)^T + bias.
// 128x128 tile, BK=32, 4 waves (2x2), 4x4 of 16x16x32 MFMA per wave.
// Double-buffered LDS; staging via global_load_lds dwordx4 (async DMA,
// no VGPR round-trip). 2-phase schedule: issue next-tile DMA, then
// ds_read+MFMA current tile, then one __syncthreads (compiler emits
// vmcnt(0) drain there, per m97).
// LDS swizzle kept from the verified kernel via PRE-SWIZZLED GLOBAL SOURCE
// (m173 pattern; LDS dest stays linear as global_load_lds requires):
// linear slot s of row r receives global chunk s ^ ((r>>1)&3);
// fragment ds_read_b128 uses slot quad ^ ((tm>>1)&3).
// ---------------------------------------------------------------------------
template <bool OUTF32>
__global__ __launch_bounds__(256) void gemm_bt2(
    const u16* __restrict__ A, int lda, const u16* __restrict__ BT,
    void* __restrict__ Cv, int N, int K, const float* __restrict__ bias) {
  __shared__ __align__(16) u16 As[2][128 * 32];
  __shared__ __align__(16) u16 Bs[2][128 * 32];

  const int tid  = threadIdx.x;
  const int wave = tid >> 6;
  const int lane = tid & 63;
  const int waveM = wave & 1, waveN = wave >> 1;

  const int mBase = blockIdx.y * 128;
  const int nBase = blockIdx.x * 128;

  // staging source: lane covers row (l>>2) of a 16-row slab, linear LDS slot
  // (l&3), sourcing global chunk cg = slot ^ ((row>>1)&3)
  const int l4 = lane >> 2;
  const int cg = (lane & 3) ^ ((lane >> 3) & 3);

  const u16* aS0 = A  + (size_t)(mBase + wave * 16 + l4) * lda + cg * 8;
  const u16* aS1 = aS0 + (size_t)64 * lda;
  const u16* bS0 = BT + (size_t)(nBase + wave * 16 + l4) * K + cg * 8;
  const u16* bS1 = bS0 + (size_t)64 * K;

  // wave-uniform LDS dest bases (lane*16B implicit in global_load_lds)
  u16* aD0 = &As[0][wave * 512];
  u16* aD1 = &As[0][2048 + wave * 512];
  u16* bD0 = &Bs[0][wave * 512];
  u16* bD1 = &Bs[0][2048 + wave * 512];

  // fragment read: row tm of each 16-row tile, quad selects k-chunk (swizzled)
  const int tm = lane & 15;
  const int quad = lane >> 4;
  const int rslot = quad ^ ((tm >> 1) & 3);
  const int aOff = (waveM * 64 + tm) * 32 + rslot * 8;
  const int bOff = (waveN * 64 + tm) * 32 + rslot * 8;

  f32x4 acc[4][4];
#pragma unroll
  for (int i = 0; i < 4; i++)
#pragma unroll
    for (int j = 0; j < 4; j++) acc[i][j] = (f32x4){0.f, 0.f, 0.f, 0.f};

  // prologue: stage K-tile 0 into buf0
  gll16(aS0, aD0);
  gll16(aS1, aD1);
  gll16(bS0, bD0);
  gll16(bS1, bD1);
  __syncthreads();  // vmcnt(0) drain emitted here by compiler

  int cur = 0;
  for (int k0 = 32; k0 < K; k0 += 32) {
    const int nxt = cur ^ 1;
    // issue next-tile DMA first; stays in flight across ds_read+MFMA
    gll16(aS0 + k0, aD0 + nxt * 4096);
    gll16(aS1 + k0, aD1 + nxt * 4096);
    gll16(bS0 + k0, bD0 + nxt * 4096);
    gll16(bS1 + k0, bD1 + nxt * 4096);

    const u16* aR = &As[cur][aOff];
    const u16* bR = &Bs[cur][bOff];
    bf16x8 af[4], bf[4];
#pragma unroll
    for (int i = 0; i < 4; i++) {
      af[i] = *(const bf16x8*)(aR + i * 512);
      bf[i] = *(const bf16x8*)(bR + i * 512);
    }
#pragma unroll
    for (int i = 0; i < 4; i++)
#pragma unroll
      for (int j = 0; j < 4; j++)
        acc[i][j] = __builtin_amdgcn_mfma_f32_16x16x32_bf16(af[i], bf[j], acc[i][j], 0, 0, 0);

    __syncthreads();  // next tile staged + this tile's reads complete
    cur = nxt;
  }

  {  // epilogue K-tile (already staged & visible)
    const u16* aR = &As[cur][aOff];
    const u16* bR = &Bs[cur][bOff];
    bf16x8 af[4], bf[4];
#pragma unroll
    for (int i = 0; i < 4; i++) {
      af[i] = *(const bf16x8*)(aR + i * 512);
      bf[i] = *(const bf16x8*)(bR + i * 512);
    }
#pragma unroll
    for (int i = 0; i < 4; i++)
#pragma unroll
      for (int j = 0; j < 4; j++)
        acc[i][j] = __builtin_amdgcn_mfma_f32_16x16x32_bf16(af[i], bf[j], acc[i][j], 0, 0, 0);
  }

  float bi[4] = {0.f, 0.f, 0.f, 0.f};
  if (bias != nullptr) {
#pragma unroll
    for (int j = 0; j < 4; j++) bi[j] = bias[nBase + waveN * 64 + j * 16 + tm];
  }
  // C/D layout: col = lane&15, row = quad*4 + reg (m89/m91-verified)
#pragma unroll
  for (int i = 0; i < 4; i++) {
    int row0 = mBase + waveM * 64 + i * 16 + quad * 4;
#pragma unroll
    for (int j = 0; j < 4; j++) {
      int col = nBase + waveN * 64 + j * 16 + tm;
#pragma unroll
      for (int r = 0; r < 4; r++) {
        float v = acc[i][j][r] + bi[j];
        if (OUTF32)
          ((float*)Cv)[(size_t)(row0 + r) * N + col] = v;
        else
          ((u16*)Cv)[(size_t)(row0 + r) * N + col] = f2bf(v);
      }
    }
  }
}

// ---------------------------------------------------------------------------
// Cross-replica attention. One wave per (b, s, hk); 4 q-heads (h%HK==hk) share
// this K/V head. Lane t holds dims (t, t+64) = the RoPE rotation pair.
// O is written IN-PLACE over the Q columns of QKV (race-free per hk).
// ---------------------------------------------------------------------------
__global__ __launch_bounds__(64) void attn_xreplica(
    u16* __restrict__ QKV, const float* __restrict__ cosb,
    const float* __restrict__ sinb) {
  const int blk = blockIdx.x;
  const int s  = blk & (S_ - 1);
  const int hk = (blk >> 11) & (HK_ - 1);
  const int b  = blk >> 13;
  const int t  = threadIdx.x;  // 0..63
  const int d0 = t, d1 = t + 64;

  u16* rp[P_];
  float kr[P_][2], vv[P_][2], cs[P_][2], sn[P_][2];
#pragma unroll
  for (int p = 0; p < P_; p++) {
    rp[p] = QKV + ((size_t)((p * B_ + b) * S_ + s)) * NQKV;
    float c0 = cosb[(b * P_ + p) * DH_ + d0];
    float c1 = cosb[(b * P_ + p) * DH_ + d1];
    float s0 = sinb[(b * P_ + p) * DH_ + d0];
    float s1 = sinb[(b * P_ + p) * DH_ + d1];
    cs[p][0] = c0; cs[p][1] = c1; sn[p][0] = s0; sn[p][1] = s1;
    float k0 = bf2f(rp[p][H_ * DH_ + hk * DH_ + d0]);
    float k1 = bf2f(rp[p][H_ * DH_ + hk * DH_ + d1]);
    kr[p][0] = k0 * c0 - k1 * s0;
    kr[p][1] = k1 * c1 + k0 * s1;
    vv[p][0] = bf2f(rp[p][(H_ + HK_) * DH_ + hk * DH_ + d0]);
    vv[p][1] = bf2f(rp[p][(H_ + HK_) * DH_ + hk * DH_ + d1]);
  }

  const float scale = 0.08838834764831845f;  // DH^-0.5
#pragma unroll
  for (int hi = 0; hi < 4; hi++) {
    const int h = hk + hi * HK_;
    float qr[P_][2];
#pragma unroll
    for (int p = 0; p < P_; p++) {
      float q0 = bf2f(rp[p][h * DH_ + d0]);
      float q1 = bf2f(rp[p][h * DH_ + d1]);
      qr[p][0] = q0 * cs[p][0] - q1 * sn[p][0];
      qr[p][1] = q1 * cs[p][1] + q0 * sn[p][1];
    }
    float sc[P_][P_];
#pragma unroll
    for (int pq = 0; pq < P_; pq++)
#pragma unroll
      for (int pk = 0; pk < P_; pk++) {
        float v = qr[pq][0] * kr[pk][0] + qr[pq][1] * kr[pk][1];
#pragma unroll
        for (int off = 32; off >= 1; off >>= 1) v += __shfl_xor(v, off, 64);
        sc[pq][pk] = v;
      }
#pragma unroll
    for (int pq = 0; pq < P_; pq++) {
      float x0 = sc[pq][0] * scale, x1 = sc[pq][1] * scale;
      float x2 = sc[pq][2] * scale, x3 = sc[pq][3] * scale;
      float m = fmaxf(fmaxf(x0, x1), fmaxf(x2, x3));
      float e0 = __expf(x0 - m), e1 = __expf(x1 - m);
      float e2 = __expf(x2 - m), e3 = __expf(x3 - m);
      float inv = 1.0f / (e0 + e1 + e2 + e3);
      float w0 = e0 * inv, w1 = e1 * inv, w2 = e2 * inv, w3 = e3 * inv;
      float o0 = w0 * vv[0][0] + w1 * vv[1][0] + w2 * vv[2][0] + w3 * vv[3][0];
      float o1 = w0 * vv[0][1] + w1 * vv[1][1] + w2 * vv[2][1] + w3 * vv[3][1];
      u16* orow = rp[pq] + h * DH_;
      orow[d0] = f2bf(o0);
      orow[d1] = f2bf(o1);
    }
  }
}

// ---------------------------------------------------------------------------
extern "C" void kernel_launch(void* const* d_in, const int* in_sizes, int n_in,
                              void* d_out, int out_size, void* d_ws, size_t ws_size,
                              hipStream_t stream) {
  const float* hs   = (const float*)d_in[0];
  const float* cosb = (const float*)d_in[1];
  const float* sinb = (const float*)d_in[2];
  const float* Wq   = (const float*)d_in[3];
  const float* bq   = (const float*)d_in[4];
  const float* Wk   = (const float*)d_in[5];
  const float* bk   = (const float*)d_in[6];
  const float* Wv   = (const float*)d_in[7];
  const float* bv   = (const float*)d_in[8];
  const float* Wo   = (const float*)d_in[9];

  // workspace layout: ~121.7 MB base + 67.1 MB hs_bf16 (fast path)
  u16*   WqkvT = (u16*)d_ws;                        // 3072 x 2048 bf16
  u16*   WoT   = WqkvT + (size_t)NQKV * K_;         // 2048 x 2048 bf16
  float* biasQ = (float*)(WoT + (size_t)D_ * K_);   // 3072 fp32 (+pad)
  u16*   QKV   = (u16*)(biasQ + 4096);              // 16384 x 3072 bf16 (O in-place)
  u16*   hsb   = QKV + (size_t)M_ * NQKV;           // 16384 x 2048 bf16
  const size_t need = (size_t)((char*)(hsb + (size_t)M_ * D_) - (char*)d_ws);

  dim3 tb(32, 8);
  transpose_f32_bf16<<<dim3(64, 64), tb, 0, stream>>>(Wq, WqkvT, D_, H_ * DH_, 0, K_);
  transpose_f32_bf16<<<dim3(16, 64), tb, 0, stream>>>(Wk, WqkvT, D_, HK_ * DH_,
                                                      (size_t)(H_ * DH_) * K_, K_);
  transpose_f32_bf16<<<dim3(16, 64), tb, 0, stream>>>(Wv, WqkvT, D_, HK_ * DH_,
                                                      (size_t)((H_ + HK_) * DH_) * K_, K_);
  transpose_f32_bf16<<<dim3(64, 64), tb, 0, stream>>>(Wo, WoT, H_ * DH_, D_, 0, K_);
  build_bias<<<12, 256, 0, stream>>>(bq, bk, bv, biasQ);

  if (ws_size >= need) {
    // fast path: pre-convert A once, then global_load_lds-staged GEMM
    f32_to_bf16<<<2048, 256, 0, stream>>>(hs, hsb, (size_t)M_ * D_ / 8);
    gemm_bt2<false><<<dim3(NQKV / 128, M_ / 128), 256, 0, stream>>>(
        hsb, K_, WqkvT, (void*)QKV, NQKV, K_, biasQ);
  } else {
    // fallback: reg-staging GEMM with inline fp32->bf16 conversion
    gemm_bt<true, false><<<dim3(NQKV / 128, M_ / 128), 256, 0, stream>>>(
        (const void*)hs, K_, WqkvT, (void*)QKV, NQKV, K_, biasQ);
  }

  // RoPE + 4x4 cross-replica attention, O written over Q columns
  attn_xreplica<<<B_ * HK_ * S_, 64, 0, stream>>>(QKV, cosb, sinb);

  // out = O @ Wo   (A = QKV's Q columns bf16, lda = 3072; C fp32 = d_out)
  gemm_bt2<true><<<dim3(D_ / 128, M_ / 128), 256, 0, stream>>>(
      QKV, NQKV, WoT, d_out, D_, K_, nullptr);
}

// Round 2
// 673.822 us; speedup vs baseline: 1.2275x; 1.1423x over previous
//
#include <hip/hip_runtime.h>
#include <stdint.h>

typedef unsigned short u16;
typedef __bf16 bf16x8 __attribute__((ext_vector_type(8)));
typedef float f32x4 __attribute__((ext_vector_type(4)));
typedef uint32_t u32x4 __attribute__((ext_vector_type(4)));

// ---- problem constants (fixed by the reference) ----
constexpr int P_  = 4, B_ = 2, S_ = 2048, D_ = 2048;
constexpr int H_  = 16, HK_ = 4, DH_ = 128;
constexpr int M_  = P_ * B_ * S_;            // 16384 rows of hidden_states
constexpr int NQKV = (H_ + 2 * HK_) * DH_;   // 3072 fused QKV columns
constexpr int K_  = D_;                      // 2048

__device__ __forceinline__ float bf2f(u16 u) {
  union { unsigned int i; float f; } v; v.i = ((unsigned int)u) << 16; return v.f;
}
__device__ __forceinline__ u16 f2bf(float f) {
  union { float f; unsigned int i; } v; v.f = f;
  unsigned int r = v.i + 0x7fffu + ((v.i >> 16) & 1u);  // RNE
  return (u16)(r >> 16);
}
__device__ __forceinline__ uint32_t pkbf(float lo, float hi) {
  return (uint32_t)f2bf(lo) | ((uint32_t)f2bf(hi) << 16);
}

// async global->LDS, 16B per lane; LDS dest is wave-uniform base + lane*16
__device__ __forceinline__ void gll16(const u16* g, u16* l) {
  __builtin_amdgcn_global_load_lds(
      (const __attribute__((address_space(1))) uint32_t*)g,
      (__attribute__((address_space(3))) uint32_t*)l, 16, 0, 0);
}

// ---------------------------------------------------------------------------
// Tiled transpose + fp32->bf16 convert: src fp32 (rows x cols) ->
// dst bf16 [dstOff + c*ld + r]
// ---------------------------------------------------------------------------
__global__ __launch_bounds__(256) void transpose_f32_bf16(
    const float* __restrict__ src, u16* __restrict__ dst,
    int rows, int cols, size_t dstOff, int ld) {
  __shared__ float tile[32][33];
  int c0 = blockIdx.x * 32, r0 = blockIdx.y * 32;
  int tx = threadIdx.x, ty = threadIdx.y;  // 32 x 8
#pragma unroll
  for (int i = 0; i < 32; i += 8)
    tile[ty + i][tx] = src[(size_t)(r0 + ty + i) * cols + (c0 + tx)];
  __syncthreads();
#pragma unroll
  for (int i = 0; i < 32; i += 8)
    dst[dstOff + (size_t)(c0 + ty + i) * ld + (r0 + tx)] = f2bf(tile[tx][ty + i]);
}

// fp32 -> bf16 bulk convert (vectorized, grid-stride)
__global__ __launch_bounds__(256) void f32_to_bf16(
    const float* __restrict__ src, u16* __restrict__ dst, size_t n8) {
  size_t i = (size_t)blockIdx.x * 256 + threadIdx.x;
  size_t stride = (size_t)gridDim.x * 256;
  for (; i < n8; i += stride) {
    f32x4 a = ((const f32x4*)src)[2 * i];
    f32x4 b = ((const f32x4*)src)[2 * i + 1];
    u32x4 o = (u32x4){pkbf(a[0], a[1]), pkbf(a[2], a[3]),
                      pkbf(b[0], b[1]), pkbf(b[2], b[3])};
    ((u32x4*)dst)[i] = o;
  }
}

// concat bq|bk|bv (fp32) -> bias[3072] fp32
__global__ void build_bias(const float* __restrict__ bq, const float* __restrict__ bk,
                           const float* __restrict__ bv, float* __restrict__ bias) {
  int n = blockIdx.x * 256 + threadIdx.x;
  if (n < NQKV)
    bias[n] = (n < H_ * DH_) ? bq[n]
            : (n < H_ * DH_ + HK_ * DH_) ? bk[n - H_ * DH_]
            : bv[n - H_ * DH_ - HK_ * DH_];
}

// ---------------------------------------------------------------------------
// 8-phase 256x256 GEMM (m194-m204 template, plain HIP):
//   C(M x N) = A(bf16, M x K [lda]) * BT(bf16, N x K)^T + bias
// BK=64, 8 waves (2M x 4N), per-wave 128x64 output = 8x4 frags of 16x16.
// LDS: 2 slots x {A,B} x 2 halves x (128 rows x 64) bf16 = 128 KiB (dynamic).
// Staging: global_load_lds dwordx4; LDS dest linear; k-chunk XOR swizzle
// (slot ^= row&7 at 16B granularity) applied on the GLOBAL source (m173) and
// on the ds_read address -> conflict-free under the 8-lane-group b128 model.
// Per K-tile: 4 phases {ds_read | stage 1 half-tile | barrier | lgkmcnt(0) |
// setprio(1) 16xMFMA setprio(0) | barrier}; reads 12/12/0/0 so the slot is
// fully consumed by the ph2-ending barrier => ph3/ph4 restage into it is
// formally race-free. Counted s_waitcnt vmcnt(4) once per K-tile (never 0
// mid-loop). Prefetch: H2,H3 of tile t+1 in ph1/ph2, H0,H1 of t+2 in ph3/ph4.
// ---------------------------------------------------------------------------
#define MM16(AF, BF, I0)                                                      \
  {                                                                           \
    _Pragma("unroll") for (int i = 0; i < 4; i++) {                           \
      _Pragma("unroll") for (int j = 0; j < 4; j++) {                         \
        acc[(I0) + i][j] = __builtin_amdgcn_mfma_f32_16x16x32_bf16(           \
            AF[(I0) + i], BF[j], acc[(I0) + i][j], 0, 0, 0);                  \
      }                                                                       \
    }                                                                         \
  }

template <bool OUTF32>
__global__ __launch_bounds__(512, 2) void gemm8(
    const u16* __restrict__ A, int lda, const u16* __restrict__ BT,
    void* __restrict__ Cv, int N, int K, const float* __restrict__ bias,
    int nbx) {
  extern __shared__ u16 Ls[];  // [slot][ab][half][8192] = 131072 B

  const int tid  = threadIdx.x;
  const int wid  = tid >> 6;
  const int lane = tid & 63;
  const int wm = wid >> 2, wn = wid & 3;
  const int tm = lane & 15, quad = lane >> 4;

  // XCD-aware bijective block swizzle (m204)
  const int nwg = gridDim.x;
  const int q = nwg >> 3, r = nwg & 7;
  const int xcd = blockIdx.x & 7, lin = blockIdx.x >> 3;
  const int wg = (xcd < r ? xcd * (q + 1) : r * (q + 1) + (xcd - r) * q) + lin;
  const int bx = wg % nbx, by = wg / nbx;
  const int mBase = by * 256, nBase = bx * 256;

  // ---- staging addresses: tid covers 64 rows x 8 chunks per issue ----
  const int sRow  = tid >> 3;                 // 0..63
  const int chunk = (tid & 7) ^ (sRow & 7);   // inverse-swizzled k-chunk
  const u16* aSt = A  + (size_t)(mBase + sRow) * lda + chunk * 8;
  const u16* bSt = BT + (size_t)(nBase + sRow) * (size_t)K + chunk * 8;

  // ---- fragment read offsets (u16 units); pslot = (kk*4+quad)^(tm&7) ----
  const int off0 = tm * 64 + ((quad)     ^ (tm & 7)) * 8;  // kk=0
  const int off1 = tm * 64 + ((quad ^ 4) ^ (tm & 7)) * 8;  // kk=1

  f32x4 acc[8][4];
#pragma unroll
  for (int i = 0; i < 8; i++)
#pragma unroll
    for (int j = 0; j < 4; j++) acc[i][j] = (f32x4){0.f, 0.f, 0.f, 0.f};

  const int nt = K >> 6;  // K-tiles of 64

  auto stA = [&](int tile, int half) {
    const u16* s0 = aSt + (size_t)(half * 128) * lda + tile * 64;
    u16* d = Ls + (((tile & 1) * 2 + 0) * 2 + half) * 8192 + wid * 512;
    gll16(s0, d);
    gll16(s0 + (size_t)64 * lda, d + 4096);
  };
  auto stB = [&](int tile, int half) {
    const u16* s0 = bSt + (size_t)(half * 128) * (size_t)K + tile * 64;
    u16* d = Ls + (((tile & 1) * 2 + 1) * 2 + half) * 8192 + wid * 512;
    gll16(s0, d);
    gll16(s0 + (size_t)64 * K, d + 4096);
  };

  // prologue: tile0 fully (slot0), tile1 A-halves (slot1)
  stA(0, 0); stA(0, 1); stB(0, 0); stB(0, 1);
  stA(1, 0); stA(1, 1);
  asm volatile("s_waitcnt vmcnt(4)" ::: "memory");  // tile0 landed
  __builtin_amdgcn_s_barrier();

  for (int t = 0; t < nt; ++t) {
    const int s = t & 1;
    const u16* aH = Ls + ((s * 2 + 0) * 2 + wm) * 8192;
    const u16* bH = Ls + ((s * 2 + 1) * 2 + (wn >> 1)) * 8192 + (wn & 1) * 4096;
    bf16x8 af0[8], bf0[4], af1[8], bf1[4];

    // ---- phase 1: ds_read kk0 (12) | stage B-half0(t+1) | MFMA kk0 i0-3
#pragma unroll
    for (int i = 0; i < 8; i++) af0[i] = *(const bf16x8*)(aH + i * 1024 + off0);
#pragma unroll
    for (int j = 0; j < 4; j++) bf0[j] = *(const bf16x8*)(bH + j * 1024 + off0);
    if (t + 1 < nt) stB(t + 1, 0);
    __builtin_amdgcn_s_barrier();
    asm volatile("s_waitcnt lgkmcnt(0)" ::: "memory");
    __builtin_amdgcn_sched_barrier(0);
    __builtin_amdgcn_s_setprio(1);
    MM16(af0, bf0, 0);
    __builtin_amdgcn_s_setprio(0);
    __builtin_amdgcn_s_barrier();

    // ---- phase 2: ds_read kk1 (12) | stage B-half1(t+1) | MFMA kk0 i4-7
#pragma unroll
    for (int i = 0; i < 8; i++) af1[i] = *(const bf16x8*)(aH + i * 1024 + off1);
#pragma unroll
    for (int j = 0; j < 4; j++) bf1[j] = *(const bf16x8*)(bH + j * 1024 + off1);
    if (t + 1 < nt) stB(t + 1, 1);
    __builtin_amdgcn_s_barrier();
    asm volatile("s_waitcnt lgkmcnt(0)" ::: "memory");
    __builtin_amdgcn_sched_barrier(0);
    __builtin_amdgcn_s_setprio(1);
    MM16(af0, bf0, 4);
    __builtin_amdgcn_s_setprio(0);
    __builtin_amdgcn_s_barrier();
    // all LDS reads of slot s complete block-wide past this barrier

    // ---- phase 3: stage A-half0(t+2) -> slot s (consumed) | MFMA kk1 i0-3
    if (t + 2 < nt) stA(t + 2, 0);
    __builtin_amdgcn_s_barrier();
    __builtin_amdgcn_s_setprio(1);
    MM16(af1, bf1, 0);
    __builtin_amdgcn_s_setprio(0);
    __builtin_amdgcn_s_barrier();

    // ---- phase 4: stage A-half1(t+2) | MFMA kk1 i4-7 | counted vmcnt
    if (t + 2 < nt) stA(t + 2, 1);
    __builtin_amdgcn_s_barrier();
    __builtin_amdgcn_s_setprio(1);
    MM16(af1, bf1, 4);
    __builtin_amdgcn_s_setprio(0);
    if (t + 2 < nt) {
      asm volatile("s_waitcnt vmcnt(4)" ::: "memory");  // t+1 fully landed
    } else {
      asm volatile("s_waitcnt vmcnt(0)" ::: "memory");  // epilogue drain
    }
    __builtin_amdgcn_s_barrier();
  }

  float bi[4] = {0.f, 0.f, 0.f, 0.f};
  if (bias != nullptr) {
#pragma unroll
    for (int j = 0; j < 4; j++) bi[j] = bias[nBase + wn * 64 + j * 16 + tm];
  }
  // C/D layout: col = lane&15, row = quad*4 + reg (m89/m91-verified)
#pragma unroll
  for (int i = 0; i < 8; i++) {
    const int row0 = mBase + wm * 128 + i * 16 + quad * 4;
#pragma unroll
    for (int j = 0; j < 4; j++) {
      const int col = nBase + wn * 64 + j * 16 + tm;
#pragma unroll
      for (int rr = 0; rr < 4; rr++) {
        float v = acc[i][j][rr] + bi[j];
        if (OUTF32)
          ((float*)Cv)[(size_t)(row0 + rr) * N + col] = v;
        else
          ((u16*)Cv)[(size_t)(row0 + rr) * N + col] = f2bf(v);
      }
    }
  }
}

// ---------------------------------------------------------------------------
// FALLBACK ONLY (ws too small): reg-staging GEMM with inline fp32->bf16 A.
// ---------------------------------------------------------------------------
template <bool AF32, bool OUTF32>
__global__ __launch_bounds__(256) void gemm_bt(
    const void* __restrict__ Av, int lda, const u16* __restrict__ BT,
    void* __restrict__ Cv, int N, int K, const float* __restrict__ bias) {
  __shared__ __align__(16) u16 As[128 * 32];
  __shared__ __align__(16) u16 Bs[128 * 32];

  const int tid  = threadIdx.x;
  const int wave = tid >> 6;
  const int lane = tid & 63;
  const int waveM = wave & 1, waveN = wave >> 1;

  const int mBase = blockIdx.y * 128;
  const int nBase = blockIdx.x * 128;

  const int l4 = lane >> 2;
  const int cg = (lane & 3) ^ ((lane >> 3) & 3);

  const float* agf0 = nullptr; const float* agf1 = nullptr;
  const u16*   agh0 = nullptr; const u16*   agh1 = nullptr;
  if (AF32) {
    agf0 = (const float*)Av + (size_t)(mBase + wave * 16 + l4) * lda + cg * 8;
    agf1 = agf0 + (size_t)64 * lda;
  } else {
    agh0 = (const u16*)Av + (size_t)(mBase + wave * 16 + l4) * lda + cg * 8;
    agh1 = agh0 + (size_t)64 * lda;
  }
  const u16* bg0 = BT + (size_t)(nBase + wave * 16 + l4) * K + cg * 8;
  const u16* bg1 = bg0 + (size_t)64 * K;
  u16* al0 = As + wave * 512 + lane * 8;
  u16* al1 = As + 2048 + wave * 512 + lane * 8;
  u16* bl0 = Bs + wave * 512 + lane * 8;
  u16* bl1 = Bs + 2048 + wave * 512 + lane * 8;

  const int tm = lane & 15;
  const int quad = lane >> 4;
  const int rslot = quad ^ ((tm >> 1) & 3);
  const u16* aRead = As + (waveM * 64 + tm) * 32 + rslot * 8;
  const u16* bRead = Bs + (waveN * 64 + tm) * 32 + rslot * 8;

  f32x4 acc[4][4];
#pragma unroll
  for (int i = 0; i < 4; i++)
#pragma unroll
    for (int j = 0; j < 4; j++) acc[i][j] = (f32x4){0.f, 0.f, 0.f, 0.f};

  for (int k0 = 0; k0 < K; k0 += 32) {
    u32x4 ra0, ra1;
    if (AF32) {
      f32x4 lo0 = *(const f32x4*)(agf0 + k0);
      f32x4 hi0 = *(const f32x4*)(agf0 + k0 + 4);
      f32x4 lo1 = *(const f32x4*)(agf1 + k0);
      f32x4 hi1 = *(const f32x4*)(agf1 + k0 + 4);
      ra0 = (u32x4){pkbf(lo0[0], lo0[1]), pkbf(lo0[2], lo0[3]),
                    pkbf(hi0[0], hi0[1]), pkbf(hi0[2], hi0[3])};
      ra1 = (u32x4){pkbf(lo1[0], lo1[1]), pkbf(lo1[2], lo1[3]),
                    pkbf(hi1[0], hi1[1]), pkbf(hi1[2], hi1[3])};
    } else {
      ra0 = *(const u32x4*)(agh0 + k0);
      ra1 = *(const u32x4*)(agh1 + k0);
    }
    u32x4 rb0 = *(const u32x4*)(bg0 + k0);
    u32x4 rb1 = *(const u32x4*)(bg1 + k0);
    __syncthreads();
    *(u32x4*)al0 = ra0;
    *(u32x4*)al1 = ra1;
    *(u32x4*)bl0 = rb0;
    *(u32x4*)bl1 = rb1;
    __syncthreads();

    bf16x8 af[4], bf[4];
#pragma unroll
    for (int i = 0; i < 4; i++) {
      af[i] = *(const bf16x8*)(aRead + i * 512);
      bf[i] = *(const bf16x8*)(bRead + i * 512);
    }
#pragma unroll
    for (int i = 0; i < 4; i++)
#pragma unroll
      for (int j = 0; j < 4; j++)
        acc[i][j] = __builtin_amdgcn_mfma_f32_16x16x32_bf16(af[i], bf[j], acc[i][j], 0, 0, 0);
  }

  float bi[4] = {0.f, 0.f, 0.f, 0.f};
  if (bias != nullptr) {
#pragma unroll
    for (int j = 0; j < 4; j++) bi[j] = bias[nBase + waveN * 64 + j * 16 + tm];
  }
#pragma unroll
  for (int i = 0; i < 4; i++) {
    int row0 = mBase + waveM * 64 + i * 16 + quad * 4;
#pragma unroll
    for (int j = 0; j < 4; j++) {
      int col = nBase + waveN * 64 + j * 16 + tm;
#pragma unroll
      for (int r = 0; r < 4; r++) {
        float v = acc[i][j][r] + bi[j];
        if (OUTF32)
          ((float*)Cv)[(size_t)(row0 + r) * N + col] = v;
        else
          ((u16*)Cv)[(size_t)(row0 + r) * N + col] = f2bf(v);
      }
    }
  }
}

// ---------------------------------------------------------------------------
// Cross-replica attention. One wave per (b, s, hk); 4 q-heads (h%HK==hk) share
// this K/V head. Lane t holds dims (t, t+64) = the RoPE rotation pair.
// O is written IN-PLACE over the Q columns of QKV (race-free per hk).
// ---------------------------------------------------------------------------
__global__ __launch_bounds__(64) void attn_xreplica(
    u16* __restrict__ QKV, const float* __restrict__ cosb,
    const float* __restrict__ sinb) {
  const int blk = blockIdx.x;
  const int s  = blk & (S_ - 1);
  const int hk = (blk >> 11) & (HK_ - 1);
  const int b  = blk >> 13;
  const int t  = threadIdx.x;  // 0..63
  const int d0 = t, d1 = t + 64;

  u16* rp[P_];
  float kr[P_][2], vv[P_][2], cs[P_][2], sn[P_][2];
#pragma unroll
  for (int p = 0; p < P_; p++) {
    rp[p] = QKV + ((size_t)((p * B_ + b) * S_ + s)) * NQKV;
    float c0 = cosb[(b * P_ + p) * DH_ + d0];
    float c1 = cosb[(b * P_ + p) * DH_ + d1];
    float s0 = sinb[(b * P_ + p) * DH_ + d0];
    float s1 = sinb[(b * P_ + p) * DH_ + d1];
    cs[p][0] = c0; cs[p][1] = c1; sn[p][0] = s0; sn[p][1] = s1;
    float k0 = bf2f(rp[p][H_ * DH_ + hk * DH_ + d0]);
    float k1 = bf2f(rp[p][H_ * DH_ + hk * DH_ + d1]);
    kr[p][0] = k0 * c0 - k1 * s0;
    kr[p][1] = k1 * c1 + k0 * s1;
    vv[p][0] = bf2f(rp[p][(H_ + HK_) * DH_ + hk * DH_ + d0]);
    vv[p][1] = bf2f(rp[p][(H_ + HK_) * DH_ + hk * DH_ + d1]);
  }

  const float scale = 0.08838834764831845f;  // DH^-0.5
#pragma unroll
  for (int hi = 0; hi < 4; hi++) {
    const int h = hk + hi * HK_;
    float qr[P_][2];
#pragma unroll
    for (int p = 0; p < P_; p++) {
      float q0 = bf2f(rp[p][h * DH_ + d0]);
      float q1 = bf2f(rp[p][h * DH_ + d1]);
      qr[p][0] = q0 * cs[p][0] - q1 * sn[p][0];
      qr[p][1] = q1 * cs[p][1] + q0 * sn[p][1];
    }
    float sc[P_][P_];
#pragma unroll
    for (int pq = 0; pq < P_; pq++)
#pragma unroll
      for (int pk = 0; pk < P_; pk++) {
        float v = qr[pq][0] * kr[pk][0] + qr[pq][1] * kr[pk][1];
#pragma unroll
        for (int off = 32; off >= 1; off >>= 1) v += __shfl_xor(v, off, 64);
        sc[pq][pk] = v;
      }
#pragma unroll
    for (int pq = 0; pq < P_; pq++) {
      float x0 = sc[pq][0] * scale, x1 = sc[pq][1] * scale;
      float x2 = sc[pq][2] * scale, x3 = sc[pq][3] * scale;
      float m = fmaxf(fmaxf(x0, x1), fmaxf(x2, x3));
      float e0 = __expf(x0 - m), e1 = __expf(x1 - m);
      float e2 = __expf(x2 - m), e3 = __expf(x3 - m);
      float inv = 1.0f / (e0 + e1 + e2 + e3);
      float w0 = e0 * inv, w1 = e1 * inv, w2 = e2 * inv, w3 = e3 * inv;
      float o0 = w0 * vv[0][0] + w1 * vv[1][0] + w2 * vv[2][0] + w3 * vv[3][0];
      float o1 = w0 * vv[0][1] + w1 * vv[1][1] + w2 * vv[2][1] + w3 * vv[3][1];
      u16* orow = rp[pq] + h * DH_;
      orow[d0] = f2bf(o0);
      orow[d1] = f2bf(o1);
    }
  }
}

// ---------------------------------------------------------------------------
extern "C" void kernel_launch(void* const* d_in, const int* in_sizes, int n_in,
                              void* d_out, int out_size, void* d_ws, size_t ws_size,
                              hipStream_t stream) {
  const float* hs   = (const float*)d_in[0];
  const float* cosb = (const float*)d_in[1];
  const float* sinb = (const float*)d_in[2];
  const float* Wq   = (const float*)d_in[3];
  const float* bq   = (const float*)d_in[4];
  const float* Wk   = (const float*)d_in[5];
  const float* bk   = (const float*)d_in[6];
  const float* Wv   = (const float*)d_in[7];
  const float* bv   = (const float*)d_in[8];
  const float* Wo   = (const float*)d_in[9];

  // workspace layout: ~121.7 MB base + 67.1 MB hs_bf16 (fast path)
  u16*   WqkvT = (u16*)d_ws;                        // 3072 x 2048 bf16
  u16*   WoT   = WqkvT + (size_t)NQKV * K_;         // 2048 x 2048 bf16
  float* biasQ = (float*)(WoT + (size_t)D_ * K_);   // 3072 fp32 (+pad)
  u16*   QKV   = (u16*)(biasQ + 4096);              // 16384 x 3072 bf16 (O in-place)
  u16*   hsb   = QKV + (size_t)M_ * NQKV;           // 16384 x 2048 bf16
  const size_t need = (size_t)((char*)(hsb + (size_t)M_ * D_) - (char*)d_ws);

  dim3 tb(32, 8);
  transpose_f32_bf16<<<dim3(64, 64), tb, 0, stream>>>(Wq, WqkvT, D_, H_ * DH_, 0, K_);
  transpose_f32_bf16<<<dim3(16, 64), tb, 0, stream>>>(Wk, WqkvT, D_, HK_ * DH_,
                                                      (size_t)(H_ * DH_) * K_, K_);
  transpose_f32_bf16<<<dim3(16, 64), tb, 0, stream>>>(Wv, WqkvT, D_, HK_ * DH_,
                                                      (size_t)((H_ + HK_) * DH_) * K_, K_);
  transpose_f32_bf16<<<dim3(64, 64), tb, 0, stream>>>(Wo, WoT, H_ * DH_, D_, 0, K_);
  build_bias<<<12, 256, 0, stream>>>(bq, bk, bv, biasQ);

  if (ws_size >= need) {
    static int attrSet = 0;
    if (!attrSet) {
      hipFuncSetAttribute((const void*)gemm8<false>,
                          hipFuncAttributeMaxDynamicSharedMemorySize, 131072);
      hipFuncSetAttribute((const void*)gemm8<true>,
                          hipFuncAttributeMaxDynamicSharedMemorySize, 131072);
      attrSet = 1;
    }
    // fast path: pre-convert A once, then 8-phase 256^2 GEMMs
    f32_to_bf16<<<2048, 256, 0, stream>>>(hs, hsb, (size_t)M_ * D_ / 8);
    gemm8<false><<<dim3((NQKV / 256) * (M_ / 256)), 512, 131072, stream>>>(
        hsb, K_, WqkvT, (void*)QKV, NQKV, K_, biasQ, NQKV / 256);
    attn_xreplica<<<B_ * HK_ * S_, 64, 0, stream>>>(QKV, cosb, sinb);
    gemm8<true><<<dim3((D_ / 256) * (M_ / 256)), 512, 131072, stream>>>(
        QKV, NQKV, WoT, d_out, D_, K_, nullptr, D_ / 256);
  } else {
    // fallback: reg-staging GEMMs (no extra workspace)
    gemm_bt<true, false><<<dim3(NQKV / 128, M_ / 128), 256, 0, stream>>>(
        (const void*)hs, K_, WqkvT, (void*)QKV, NQKV, K_, biasQ);
    attn_xreplica<<<B_ * HK_ * S_, 64, 0, stream>>>(QKV, cosb, sinb);
    gemm_bt<false, true><<<dim3(D_ / 128, M_ / 128), 256, 0, stream>>>(
        (const void*)QKV, NQKV, WoT, d_out, D_, K_, nullptr);
  }
}

// Round 3
// 647.747 us; speedup vs baseline: 1.2769x; 1.0403x over previous
//
#include <hip/hip_runtime.h>
#include <stdint.h>

typedef unsigned short u16;
typedef __bf16 bf16x8 __attribute__((ext_vector_type(8)));
typedef float f32x4 __attribute__((ext_vector_type(4)));
typedef uint32_t u32x4 __attribute__((ext_vector_type(4)));

// ---- problem constants (fixed by the reference) ----
constexpr int P_  = 4, B_ = 2, S_ = 2048, D_ = 2048;
constexpr int H_  = 16, HK_ = 4, DH_ = 128;
constexpr int M_  = P_ * B_ * S_;            // 16384 rows of hidden_states
constexpr int NQKV = (H_ + 2 * HK_) * DH_;   // 3072 fused QKV columns
constexpr int K_  = D_;                      // 2048

__device__ __forceinline__ float bf2f(u16 u) {
  union { unsigned int i; float f; } v; v.i = ((unsigned int)u) << 16; return v.f;
}
__device__ __forceinline__ u16 f2bf(float f) {
  union { float f; unsigned int i; } v; v.f = f;
  unsigned int r = v.i + 0x7fffu + ((v.i >> 16) & 1u);  // RNE
  return (u16)(r >> 16);
}
__device__ __forceinline__ uint32_t pkbf(float lo, float hi) {
  return (uint32_t)f2bf(lo) | ((uint32_t)f2bf(hi) << 16);
}

// async global->LDS, 16B per lane; LDS dest is wave-uniform base + lane*16
__device__ __forceinline__ void gll16(const u16* g, u16* l) {
  __builtin_amdgcn_global_load_lds(
      (const __attribute__((address_space(1))) uint32_t*)g,
      (__attribute__((address_space(3))) uint32_t*)l, 16, 0, 0);
}

// ---------------------------------------------------------------------------
// Tiled transpose + fp32->bf16 convert: src fp32 (rows x cols) ->
// dst bf16 [dstOff + c*ld + r]
// ---------------------------------------------------------------------------
__global__ __launch_bounds__(256) void transpose_f32_bf16(
    const float* __restrict__ src, u16* __restrict__ dst,
    int rows, int cols, size_t dstOff, int ld) {
  __shared__ float tile[32][33];
  int c0 = blockIdx.x * 32, r0 = blockIdx.y * 32;
  int tx = threadIdx.x, ty = threadIdx.y;  // 32 x 8
#pragma unroll
  for (int i = 0; i < 32; i += 8)
    tile[ty + i][tx] = src[(size_t)(r0 + ty + i) * cols + (c0 + tx)];
  __syncthreads();
#pragma unroll
  for (int i = 0; i < 32; i += 8)
    dst[dstOff + (size_t)(c0 + ty + i) * ld + (r0 + tx)] = f2bf(tile[tx][ty + i]);
}

// fp32 -> bf16 bulk convert (vectorized, grid-stride)
__global__ __launch_bounds__(256) void f32_to_bf16(
    const float* __restrict__ src, u16* __restrict__ dst, size_t n8) {
  size_t i = (size_t)blockIdx.x * 256 + threadIdx.x;
  size_t stride = (size_t)gridDim.x * 256;
  for (; i < n8; i += stride) {
    f32x4 a = ((const f32x4*)src)[2 * i];
    f32x4 b = ((const f32x4*)src)[2 * i + 1];
    u32x4 o = (u32x4){pkbf(a[0], a[1]), pkbf(a[2], a[3]),
                      pkbf(b[0], b[1]), pkbf(b[2], b[3])};
    ((u32x4*)dst)[i] = o;
  }
}

// concat bq|bk|bv (fp32) -> bias[3072] fp32
__global__ void build_bias(const float* __restrict__ bq, const float* __restrict__ bk,
                           const float* __restrict__ bv, float* __restrict__ bias) {
  int n = blockIdx.x * 256 + threadIdx.x;
  if (n < NQKV)
    bias[n] = (n < H_ * DH_) ? bq[n]
            : (n < H_ * DH_ + HK_ * DH_) ? bk[n - H_ * DH_]
            : bv[n - H_ * DH_ - HK_ * DH_];
}

// ---------------------------------------------------------------------------
// 8-phase 256x256 GEMM (m194-m204 template, plain HIP):
//   C(M x N) = A(bf16, M x K [lda]) * BT(bf16, N x K)^T + bias
// BK=64, 8 waves (2M x 4N), per-wave 128x64 output = 8x4 frags of 16x16.
// LDS: 2 slots x {A,B} x 2 halves x 8192 u16 = 128 KiB (dynamic).
// Staging: global_load_lds dwordx4; LDS dest linear; k-chunk XOR swizzle
// (slot ^= row&7 at 16B granularity) applied on the GLOBAL source (m173) and
// on the ds_read address -> conflict-free b128 reads (measured 0 conflicts).
// Balanced phase schedule (reads 8/8/8/0 per K-tile, m201 pattern):
//   ph1: read af0[0:4]+bf0 | stage B(t+1,h0) | bar | lgkm0 | MFMA kk0 lo | bar
//   ph2: read af0[4:8]+af1[0:4] | stage B(t+1,h1) | ... | MFMA kk0 hi | bar
//   ph3: read af1[4:8]+bf1 | (no stage)       | ... | MFMA kk1 lo | bar
//   ph4: stage A(t+2,h0)+A(t+2,h1) | bar | MFMA kk1 hi | vmcnt(4) | bar
// Race proof: all slot-s LDS reads are lgkmcnt(0)-complete before ph3's
// ending barrier; A(t+2) restage into slot s issues only after it. B(t+1)
// goes to slot s^1 (reads finished in iter t-1). vmcnt(4) at ph4 drains
// exactly tile t+1 (invariant: A(t+1):4 loads in flight at iter start).
// ---------------------------------------------------------------------------
#define MM16(AF, BF, I0)                                                      \
  {                                                                           \
    _Pragma("unroll") for (int i = 0; i < 4; i++) {                           \
      _Pragma("unroll") for (int j = 0; j < 4; j++) {                         \
        acc[(I0) + i][j] = __builtin_amdgcn_mfma_f32_16x16x32_bf16(           \
            AF[(I0) + i], BF[j], acc[(I0) + i][j], 0, 0, 0);                  \
      }                                                                       \
    }                                                                         \
  }

template <bool OUTF32>
__global__ __launch_bounds__(512, 2) void gemm8(
    const u16* __restrict__ A, int lda, const u16* __restrict__ BT,
    void* __restrict__ Cv, int N, int K, const float* __restrict__ bias,
    int nbx) {
  extern __shared__ u16 Ls[];  // [slot][ab][half][8192] = 131072 B

  const int tid  = threadIdx.x;
  const int wid  = tid >> 6;
  const int lane = tid & 63;
  const int wm = wid >> 2, wn = wid & 3;
  const int tm = lane & 15, quad = lane >> 4;

  // XCD-aware bijective block swizzle (m204)
  const int nwg = gridDim.x;
  const int q = nwg >> 3, r = nwg & 7;
  const int xcd = blockIdx.x & 7, lin = blockIdx.x >> 3;
  const int wg = (xcd < r ? xcd * (q + 1) : r * (q + 1) + (xcd - r) * q) + lin;
  const int bx = wg % nbx, by = wg / nbx;
  const int mBase = by * 256, nBase = bx * 256;

  // ---- staging addresses: tid covers 64 rows x 8 chunks per issue ----
  const int sRow  = tid >> 3;                 // 0..63
  const int chunk = (tid & 7) ^ (sRow & 7);   // inverse-swizzled k-chunk
  const u16* aSt = A  + (size_t)(mBase + sRow) * lda + chunk * 8;
  const u16* bSt = BT + (size_t)(nBase + sRow) * (size_t)K + chunk * 8;

  // ---- fragment read offsets (u16 units); pslot = (kk*4+quad)^(tm&7) ----
  const int off0 = tm * 64 + ((quad)     ^ (tm & 7)) * 8;  // kk=0
  const int off1 = tm * 64 + ((quad ^ 4) ^ (tm & 7)) * 8;  // kk=1

  f32x4 acc[8][4];
#pragma unroll
  for (int i = 0; i < 8; i++)
#pragma unroll
    for (int j = 0; j < 4; j++) acc[i][j] = (f32x4){0.f, 0.f, 0.f, 0.f};

  const int nt = K >> 6;  // K-tiles of 64

  auto stA = [&](int tile, int half) {
    const u16* s0 = aSt + (size_t)(half * 128) * lda + tile * 64;
    u16* d = Ls + (((tile & 1) * 2 + 0) * 2 + half) * 8192 + wid * 512;
    gll16(s0, d);
    gll16(s0 + (size_t)64 * lda, d + 4096);
  };
  auto stB = [&](int tile, int half) {
    const u16* s0 = bSt + (size_t)(half * 128) * (size_t)K + tile * 64;
    u16* d = Ls + (((tile & 1) * 2 + 1) * 2 + half) * 8192 + wid * 512;
    gll16(s0, d);
    gll16(s0 + (size_t)64 * K, d + 4096);
  };

  // prologue: tile0 fully (slot0), tile1 A-halves (slot1)
  stA(0, 0); stA(0, 1); stB(0, 0); stB(0, 1);
  stA(1, 0); stA(1, 1);
  asm volatile("s_waitcnt vmcnt(4)" ::: "memory");  // tile0 landed
  __builtin_amdgcn_s_barrier();

  for (int t = 0; t < nt; ++t) {
    const int s = t & 1;
    const u16* aH = Ls + ((s * 2 + 0) * 2 + wm) * 8192;
    const u16* bH = Ls + ((s * 2 + 1) * 2 + (wn >> 1)) * 8192 + (wn & 1) * 4096;
    bf16x8 af0[8], bf0[4], af1[8], bf1[4];

    // ---- phase 1: read af0[0:4]+bf0 (8) | stage B(t+1,h0) | MFMA kk0 lo
#pragma unroll
    for (int i = 0; i < 4; i++) af0[i] = *(const bf16x8*)(aH + i * 1024 + off0);
#pragma unroll
    for (int j = 0; j < 4; j++) bf0[j] = *(const bf16x8*)(bH + j * 1024 + off0);
    if (t + 1 < nt) stB(t + 1, 0);
    __builtin_amdgcn_s_barrier();
    asm volatile("s_waitcnt lgkmcnt(0)" ::: "memory");
    __builtin_amdgcn_sched_barrier(0);
    __builtin_amdgcn_s_setprio(1);
    MM16(af0, bf0, 0);
    __builtin_amdgcn_s_setprio(0);
    __builtin_amdgcn_s_barrier();

    // ---- phase 2: read af0[4:8]+af1[0:4] (8) | stage B(t+1,h1) | MFMA kk0 hi
#pragma unroll
    for (int i = 4; i < 8; i++) af0[i] = *(const bf16x8*)(aH + i * 1024 + off0);
#pragma unroll
    for (int i = 0; i < 4; i++) af1[i] = *(const bf16x8*)(aH + i * 1024 + off1);
    if (t + 1 < nt) stB(t + 1, 1);
    __builtin_amdgcn_s_barrier();
    asm volatile("s_waitcnt lgkmcnt(0)" ::: "memory");
    __builtin_amdgcn_sched_barrier(0);
    __builtin_amdgcn_s_setprio(1);
    MM16(af0, bf0, 4);
    __builtin_amdgcn_s_setprio(0);
    __builtin_amdgcn_s_barrier();

    // ---- phase 3: read af1[4:8]+bf1 (8) | no stage | MFMA kk1 lo
    // (all slot-s LDS reads complete at this phase's lgkmcnt(0))
#pragma unroll
    for (int i = 4; i < 8; i++) af1[i] = *(const bf16x8*)(aH + i * 1024 + off1);
#pragma unroll
    for (int j = 0; j < 4; j++) bf1[j] = *(const bf16x8*)(bH + j * 1024 + off1);
    __builtin_amdgcn_s_barrier();
    asm volatile("s_waitcnt lgkmcnt(0)" ::: "memory");
    __builtin_amdgcn_sched_barrier(0);
    __builtin_amdgcn_s_setprio(1);
    MM16(af1, bf1, 0);
    __builtin_amdgcn_s_setprio(0);
    __builtin_amdgcn_s_barrier();

    // ---- phase 4: stage A(t+2,h0)+A(t+2,h1) into consumed slot s |
    //              MFMA kk1 hi | counted vmcnt
    if (t + 2 < nt) { stA(t + 2, 0); stA(t + 2, 1); }
    __builtin_amdgcn_s_barrier();
    __builtin_amdgcn_s_setprio(1);
    MM16(af1, bf1, 4);
    __builtin_amdgcn_s_setprio(0);
    if (t + 2 < nt) {
      asm volatile("s_waitcnt vmcnt(4)" ::: "memory");  // t+1 fully landed
    } else {
      asm volatile("s_waitcnt vmcnt(0)" ::: "memory");  // epilogue drain
    }
    __builtin_amdgcn_s_barrier();
  }

  float bi[4] = {0.f, 0.f, 0.f, 0.f};
  if (bias != nullptr) {
#pragma unroll
    for (int j = 0; j < 4; j++) bi[j] = bias[nBase + wn * 64 + j * 16 + tm];
  }
  // C/D layout: col = lane&15, row = quad*4 + reg (m89/m91-verified)
#pragma unroll
  for (int i = 0; i < 8; i++) {
    const int row0 = mBase + wm * 128 + i * 16 + quad * 4;
#pragma unroll
    for (int j = 0; j < 4; j++) {
      const int col = nBase + wn * 64 + j * 16 + tm;
#pragma unroll
      for (int rr = 0; rr < 4; rr++) {
        float v = acc[i][j][rr] + bi[j];
        if (OUTF32)
          ((float*)Cv)[(size_t)(row0 + rr) * N + col] = v;
        else
          ((u16*)Cv)[(size_t)(row0 + rr) * N + col] = f2bf(v);
      }
    }
  }
}

// ---------------------------------------------------------------------------
// FALLBACK ONLY (ws too small): reg-staging GEMM with inline fp32->bf16 A.
// ---------------------------------------------------------------------------
template <bool AF32, bool OUTF32>
__global__ __launch_bounds__(256) void gemm_bt(
    const void* __restrict__ Av, int lda, const u16* __restrict__ BT,
    void* __restrict__ Cv, int N, int K, const float* __restrict__ bias) {
  __shared__ __align__(16) u16 As[128 * 32];
  __shared__ __align__(16) u16 Bs[128 * 32];

  const int tid  = threadIdx.x;
  const int wave = tid >> 6;
  const int lane = tid & 63;
  const int waveM = wave & 1, waveN = wave >> 1;

  const int mBase = blockIdx.y * 128;
  const int nBase = blockIdx.x * 128;

  const int l4 = lane >> 2;
  const int cg = (lane & 3) ^ ((lane >> 3) & 3);

  const float* agf0 = nullptr; const float* agf1 = nullptr;
  const u16*   agh0 = nullptr; const u16*   agh1 = nullptr;
  if (AF32) {
    agf0 = (const float*)Av + (size_t)(mBase + wave * 16 + l4) * lda + cg * 8;
    agf1 = agf0 + (size_t)64 * lda;
  } else {
    agh0 = (const u16*)Av + (size_t)(mBase + wave * 16 + l4) * lda + cg * 8;
    agh1 = agh0 + (size_t)64 * lda;
  }
  const u16* bg0 = BT + (size_t)(nBase + wave * 16 + l4) * K + cg * 8;
  const u16* bg1 = bg0 + (size_t)64 * K;
  u16* al0 = As + wave * 512 + lane * 8;
  u16* al1 = As + 2048 + wave * 512 + lane * 8;
  u16* bl0 = Bs + wave * 512 + lane * 8;
  u16* bl1 = Bs + 2048 + wave * 512 + lane * 8;

  const int tm = lane & 15;
  const int quad = lane >> 4;
  const int rslot = quad ^ ((tm >> 1) & 3);
  const u16* aRead = As + (waveM * 64 + tm) * 32 + rslot * 8;
  const u16* bRead = Bs + (waveN * 64 + tm) * 32 + rslot * 8;

  f32x4 acc[4][4];
#pragma unroll
  for (int i = 0; i < 4; i++)
#pragma unroll
    for (int j = 0; j < 4; j++) acc[i][j] = (f32x4){0.f, 0.f, 0.f, 0.f};

  for (int k0 = 0; k0 < K; k0 += 32) {
    u32x4 ra0, ra1;
    if (AF32) {
      f32x4 lo0 = *(const f32x4*)(agf0 + k0);
      f32x4 hi0 = *(const f32x4*)(agf0 + k0 + 4);
      f32x4 lo1 = *(const f32x4*)(agf1 + k0);
      f32x4 hi1 = *(const f32x4*)(agf1 + k0 + 4);
      ra0 = (u32x4){pkbf(lo0[0], lo0[1]), pkbf(lo0[2], lo0[3]),
                    pkbf(hi0[0], hi0[1]), pkbf(hi0[2], hi0[3])};
      ra1 = (u32x4){pkbf(lo1[0], lo1[1]), pkbf(lo1[2], lo1[3]),
                    pkbf(hi1[0], hi1[1]), pkbf(hi1[2], hi1[3])};
    } else {
      ra0 = *(const u32x4*)(agh0 + k0);
      ra1 = *(const u32x4*)(agh1 + k0);
    }
    u32x4 rb0 = *(const u32x4*)(bg0 + k0);
    u32x4 rb1 = *(const u32x4*)(bg1 + k0);
    __syncthreads();
    *(u32x4*)al0 = ra0;
    *(u32x4*)al1 = ra1;
    *(u32x4*)bl0 = rb0;
    *(u32x4*)bl1 = rb1;
    __syncthreads();

    bf16x8 af[4], bf[4];
#pragma unroll
    for (int i = 0; i < 4; i++) {
      af[i] = *(const bf16x8*)(aRead + i * 512);
      bf[i] = *(const bf16x8*)(bRead + i * 512);
    }
#pragma unroll
    for (int i = 0; i < 4; i++)
#pragma unroll
      for (int j = 0; j < 4; j++)
        acc[i][j] = __builtin_amdgcn_mfma_f32_16x16x32_bf16(af[i], bf[j], acc[i][j], 0, 0, 0);
  }

  float bi[4] = {0.f, 0.f, 0.f, 0.f};
  if (bias != nullptr) {
#pragma unroll
    for (int j = 0; j < 4; j++) bi[j] = bias[nBase + waveN * 64 + j * 16 + tm];
  }
#pragma unroll
  for (int i = 0; i < 4; i++) {
    int row0 = mBase + waveM * 64 + i * 16 + quad * 4;
#pragma unroll
    for (int j = 0; j < 4; j++) {
      int col = nBase + waveN * 64 + j * 16 + tm;
#pragma unroll
      for (int r = 0; r < 4; r++) {
        float v = acc[i][j][r] + bi[j];
        if (OUTF32)
          ((float*)Cv)[(size_t)(row0 + r) * N + col] = v;
        else
          ((u16*)Cv)[(size_t)(row0 + r) * N + col] = f2bf(v);
      }
    }
  }
}

// ---------------------------------------------------------------------------
// Cross-replica attention. One wave per (b, s, hk); 4 q-heads (h%HK==hk) share
// this K/V head. Lane t holds dims (t, t+64) = the RoPE rotation pair.
// O is written IN-PLACE over the Q columns of QKV (race-free per hk).
// ---------------------------------------------------------------------------
__global__ __launch_bounds__(64) void attn_xreplica(
    u16* __restrict__ QKV, const float* __restrict__ cosb,
    const float* __restrict__ sinb) {
  const int blk = blockIdx.x;
  const int s  = blk & (S_ - 1);
  const int hk = (blk >> 11) & (HK_ - 1);
  const int b  = blk >> 13;
  const int t  = threadIdx.x;  // 0..63
  const int d0 = t, d1 = t + 64;

  u16* rp[P_];
  float kr[P_][2], vv[P_][2], cs[P_][2], sn[P_][2];
#pragma unroll
  for (int p = 0; p < P_; p++) {
    rp[p] = QKV + ((size_t)((p * B_ + b) * S_ + s)) * NQKV;
    float c0 = cosb[(b * P_ + p) * DH_ + d0];
    float c1 = cosb[(b * P_ + p) * DH_ + d1];
    float s0 = sinb[(b * P_ + p) * DH_ + d0];
    float s1 = sinb[(b * P_ + p) * DH_ + d1];
    cs[p][0] = c0; cs[p][1] = c1; sn[p][0] = s0; sn[p][1] = s1;
    float k0 = bf2f(rp[p][H_ * DH_ + hk * DH_ + d0]);
    float k1 = bf2f(rp[p][H_ * DH_ + hk * DH_ + d1]);
    kr[p][0] = k0 * c0 - k1 * s0;
    kr[p][1] = k1 * c1 + k0 * s1;
    vv[p][0] = bf2f(rp[p][(H_ + HK_) * DH_ + hk * DH_ + d0]);
    vv[p][1] = bf2f(rp[p][(H_ + HK_) * DH_ + hk * DH_ + d1]);
  }

  const float scale = 0.08838834764831845f;  // DH^-0.5
#pragma unroll
  for (int hi = 0; hi < 4; hi++) {
    const int h = hk + hi * HK_;
    float qr[P_][2];
#pragma unroll
    for (int p = 0; p < P_; p++) {
      float q0 = bf2f(rp[p][h * DH_ + d0]);
      float q1 = bf2f(rp[p][h * DH_ + d1]);
      qr[p][0] = q0 * cs[p][0] - q1 * sn[p][0];
      qr[p][1] = q1 * cs[p][1] + q0 * sn[p][1];
    }
    float sc[P_][P_];
#pragma unroll
    for (int pq = 0; pq < P_; pq++)
#pragma unroll
      for (int pk = 0; pk < P_; pk++) {
        float v = qr[pq][0] * kr[pk][0] + qr[pq][1] * kr[pk][1];
#pragma unroll
        for (int off = 32; off >= 1; off >>= 1) v += __shfl_xor(v, off, 64);
        sc[pq][pk] = v;
      }
#pragma unroll
    for (int pq = 0; pq < P_; pq++) {
      float x0 = sc[pq][0] * scale, x1 = sc[pq][1] * scale;
      float x2 = sc[pq][2] * scale, x3 = sc[pq][3] * scale;
      float m = fmaxf(fmaxf(x0, x1), fmaxf(x2, x3));
      float e0 = __expf(x0 - m), e1 = __expf(x1 - m);
      float e2 = __expf(x2 - m), e3 = __expf(x3 - m);
      float inv = 1.0f / (e0 + e1 + e2 + e3);
      float w0 = e0 * inv, w1 = e1 * inv, w2 = e2 * inv, w3 = e3 * inv;
      float o0 = w0 * vv[0][0] + w1 * vv[1][0] + w2 * vv[2][0] + w3 * vv[3][0];
      float o1 = w0 * vv[0][1] + w1 * vv[1][1] + w2 * vv[2][1] + w3 * vv[3][1];
      u16* orow = rp[pq] + h * DH_;
      orow[d0] = f2bf(o0);
      orow[d1] = f2bf(o1);
    }
  }
}

// ---------------------------------------------------------------------------
extern "C" void kernel_launch(void* const* d_in, const int* in_sizes, int n_in,
                              void* d_out, int out_size, void* d_ws, size_t ws_size,
                              hipStream_t stream) {
  const float* hs   = (const float*)d_in[0];
  const float* cosb = (const float*)d_in[1];
  const float* sinb = (const float*)d_in[2];
  const float* Wq   = (const float*)d_in[3];
  const float* bq   = (const float*)d_in[4];
  const float* Wk   = (const float*)d_in[5];
  const float* bk   = (const float*)d_in[6];
  const float* Wv   = (const float*)d_in[7];
  const float* bv   = (const float*)d_in[8];
  const float* Wo   = (const float*)d_in[9];

  // workspace layout: ~121.7 MB base + 67.1 MB hs_bf16 (fast path)
  u16*   WqkvT = (u16*)d_ws;                        // 3072 x 2048 bf16
  u16*   WoT   = WqkvT + (size_t)NQKV * K_;         // 2048 x 2048 bf16
  float* biasQ = (float*)(WoT + (size_t)D_ * K_);   // 3072 fp32 (+pad)
  u16*   QKV   = (u16*)(biasQ + 4096);              // 16384 x 3072 bf16 (O in-place)
  u16*   hsb   = QKV + (size_t)M_ * NQKV;           // 16384 x 2048 bf16
  const size_t need = (size_t)((char*)(hsb + (size_t)M_ * D_) - (char*)d_ws);

  dim3 tb(32, 8);
  transpose_f32_bf16<<<dim3(64, 64), tb, 0, stream>>>(Wq, WqkvT, D_, H_ * DH_, 0, K_);
  transpose_f32_bf16<<<dim3(16, 64), tb, 0, stream>>>(Wk, WqkvT, D_, HK_ * DH_,
                                                      (size_t)(H_ * DH_) * K_, K_);
  transpose_f32_bf16<<<dim3(16, 64), tb, 0, stream>>>(Wv, WqkvT, D_, HK_ * DH_,
                                                      (size_t)((H_ + HK_) * DH_) * K_, K_);
  transpose_f32_bf16<<<dim3(64, 64), tb, 0, stream>>>(Wo, WoT, H_ * DH_, D_, 0, K_);
  build_bias<<<12, 256, 0, stream>>>(bq, bk, bv, biasQ);

  if (ws_size >= need) {
    static int attrSet = 0;
    if (!attrSet) {
      hipFuncSetAttribute((const void*)gemm8<false>,
                          hipFuncAttributeMaxDynamicSharedMemorySize, 131072);
      hipFuncSetAttribute((const void*)gemm8<true>,
                          hipFuncAttributeMaxDynamicSharedMemorySize, 131072);
      attrSet = 1;
    }
    // fast path: pre-convert A once, then 8-phase 256^2 GEMMs
    f32_to_bf16<<<2048, 256, 0, stream>>>(hs, hsb, (size_t)M_ * D_ / 8);
    gemm8<false><<<dim3((NQKV / 256) * (M_ / 256)), 512, 131072, stream>>>(
        hsb, K_, WqkvT, (void*)QKV, NQKV, K_, biasQ, NQKV / 256);
    attn_xreplica<<<B_ * HK_ * S_, 64, 0, stream>>>(QKV, cosb, sinb);
    gemm8<true><<<dim3((D_ / 256) * (M_ / 256)), 512, 131072, stream>>>(
        QKV, NQKV, WoT, d_out, D_, K_, nullptr, D_ / 256);
  } else {
    // fallback: reg-staging GEMMs (no extra workspace)
    gemm_bt<true, false><<<dim3(NQKV / 128, M_ / 128), 256, 0, stream>>>(
        (const void*)hs, K_, WqkvT, (void*)QKV, NQKV, K_, biasQ);
    attn_xreplica<<<B_ * HK_ * S_, 64, 0, stream>>>(QKV, cosb, sinb);
    gemm_bt<false, true><<<dim3(D_ / 128, M_ / 128), 256, 0, stream>>>(
        (const void*)QKV, NQKV, WoT, d_out, D_, K_, nullptr);
  }
}